// Round 15
// baseline (145.424 us; speedup 1.0000x reference)
//
#include <hip/hip_runtime.h>

typedef unsigned short u16;
typedef unsigned int u32;
typedef __attribute__((ext_vector_type(8))) __bf16 bf16v8;
typedef __attribute__((ext_vector_type(4))) __bf16 bf16v4;
typedef __attribute__((ext_vector_type(4))) float f32x4;
typedef __attribute__((ext_vector_type(16))) float f32x16;
typedef __attribute__((ext_vector_type(2))) unsigned u32x2;

#define SEQ    2048
#define NBATCH 2
#define NHEAD  16
#define HD     64
#define DM     1024
#define MROWS  4096   // NBATCH*SEQ

__device__ __forceinline__ u16 f2bf(float f) {
  unsigned int u = __float_as_uint(f);
  u += 0x7FFFu + ((u >> 16) & 1u);   // round-to-nearest-even
  return (u16)(u >> 16);
}

__device__ __forceinline__ void gll16(const void* g, void* l) {
  __builtin_amdgcn_global_load_lds(
      (__attribute__((address_space(1))) void*)g,
      (__attribute__((address_space(3))) void*)l, 16, 0, 0);
}

// ---------------- fused prep: x->bf16, 4x W->bf16, RoPE table (1 dispatch) ----------
__global__ __launch_bounds__(256) void k_prep(
    const float* __restrict__ x,
    const float* __restrict__ Wq, const float* __restrict__ Wk,
    const float* __restrict__ Wv, const float* __restrict__ Wo,
    u16* __restrict__ Xb, u16* __restrict__ Wqb, u16* __restrict__ Wkb,
    u16* __restrict__ Wvb, u16* __restrict__ Wob,
    float* __restrict__ cosT, float* __restrict__ sinT) {
  int bid = blockIdx.x;
  if (bid < MROWS * DM / 1024) {            // 4096 blocks: x f32->bf16
    int i = bid * 256 + threadIdx.x;
    float4 v = ((const float4*)x)[i];
    ushort4 o;
    o.x = f2bf(v.x); o.y = f2bf(v.y); o.z = f2bf(v.z); o.w = f2bf(v.w);
    ((ushort4*)Xb)[i] = o;
    return;
  }
  bid -= MROWS * DM / 1024;
  if (bid < 4 * (DM * DM / 1024)) {         // 4096 blocks: weights f32->bf16
    int seg = bid >> 10;
    int i = (bid & 1023) * 256 + threadIdx.x;
    const float* src = (seg == 0) ? Wq : (seg == 1) ? Wk : (seg == 2) ? Wv : Wo;
    u16* dst = (seg == 0) ? Wqb : (seg == 1) ? Wkb : (seg == 2) ? Wvb : Wob;
    float4 v = ((const float4*)src)[i];
    ushort4 o;
    o.x = f2bf(v.x); o.y = f2bf(v.y); o.z = f2bf(v.z); o.w = f2bf(v.w);
    ((ushort4*)dst)[i] = o;
    return;
  }
  bid -= 4 * (DM * DM / 1024);
  int idx = bid * 256 + threadIdx.x;        // 256 blocks: RoPE cos/sin table
  int l = idx >> 5, d = idx & 31;
  float inv = 1.0f / powf(10000.0f, (float)d * (1.0f / 32.0f));
  float ang = (float)l * inv;
  float s, c;
  sincosf(ang, &s, &c);
  cosT[idx] = c;
  sinT[idx] = s;
}

// ---------------- fused QKV projection: bias + RoPE(Q,K) + bf16 + attn layouts ------
// z=0: Q -> Qr [bh][l][d], RoPE, x(0.125*log2e) folded in
// z=1: K -> Kg [bh][kk=d/8][kv][8d], RoPE          (attn layout)
// z=2: V -> Vg [bh][kvk=kv/8][d][8kv]              (attn layout; vtrans fused)
__global__ __launch_bounds__(256) void k_gemm_qkv(
    const u16* __restrict__ A,
    const u16* W0, const u16* W1, const u16* W2,
    const float* b0, const float* b1, const float* b2,
    u16* __restrict__ Qr, u16* __restrict__ Kg, u16* __restrict__ Vg,
    const float* __restrict__ cosT, const float* __restrict__ sinT) {
  __shared__ __attribute__((aligned(16))) u16 As[128 * 64];
  __shared__ __attribute__((aligned(16))) u16 Bs[128 * 64];
  const int z = blockIdx.z;
  const u16* W = (z == 0) ? W0 : ((z == 1) ? W1 : W2);
  const float* bias = (z == 0) ? b0 : ((z == 1) ? b1 : b2);

  const int tid = threadIdx.x;
  const int lane = tid & 63, wid = tid >> 6;
  const int g = lane >> 4, c = lane & 15;
  const int wm = wid >> 1, wn = wid & 1;
  const int bm = blockIdx.x, bn = blockIdx.y;

  const f32x4 vz = {0.f, 0.f, 0.f, 0.f};
  f32x4 acc[4][4];
#pragma unroll
  for (int i = 0; i < 4; i++)
#pragma unroll
    for (int j = 0; j < 4; j++) acc[i][j] = vz;

  const int srow = tid >> 3;
  const int scb = tid & 7;

  for (int kt = 0; kt < DM / 64; ++kt) {
    __syncthreads();
#pragma unroll
    for (int cc = 0; cc < 4; ++cc) {
      int row = cc * 32 + srow;
      int sc = scb ^ (row & 7);
      gll16(A + (size_t)(bm * 128 + row) * DM + kt * 64 + sc * 8,
            &As[cc * 2048 + wid * 512]);
      gll16(W + (size_t)(bn * 128 + row) * DM + kt * 64 + sc * 8,
            &Bs[cc * 2048 + wid * 512]);
    }
    __syncthreads();
#pragma unroll
    for (int kk = 0; kk < 2; ++kk) {
      bf16v8 av[4], bv[4];
#pragma unroll
      for (int i = 0; i < 4; i++) {
        int row = wm * 64 + i * 16 + c;
        int sc = (kk * 4 + g) ^ (row & 7);
        av[i] = *(const bf16v8*)&As[row * 64 + sc * 8];
      }
#pragma unroll
      for (int j = 0; j < 4; j++) {
        int row = wn * 64 + j * 16 + c;
        int sc = (kk * 4 + g) ^ (row & 7);
        bv[j] = *(const bf16v8*)&Bs[row * 64 + sc * 8];
      }
#pragma unroll
      for (int i = 0; i < 4; i++)
#pragma unroll
        for (int j = 0; j < 4; j++)
          acc[i][j] = __builtin_amdgcn_mfma_f32_16x16x32_bf16(av[i], bv[j], acc[i][j], 0, 0, 0);
    }
  }

  if (z == 2) {
    // V: bias + bf16, write directly in attn layout [bh][kv>>3][d][kv&7]
    const int h = bn * 2 + wn;
#pragma unroll
    for (int i = 0; i < 4; i++) {
      int m0 = bm * 128 + wm * 64 + i * 16 + g * 4;
#pragma unroll
      for (int r = 0; r < 4; r++) {
        int m = m0 + r;
        int tok = m & (SEQ - 1);
        int b = m >> 11;
        size_t base = ((size_t)((b * NHEAD + h) * 256 + (tok >> 3)) * 64) * 8 + (tok & 7);
#pragma unroll
        for (int j = 0; j < 4; j++) {
          int d = j * 16 + c;
          Vg[base + (size_t)d * 8] = f2bf(acc[i][j][r] + bias[bn * 128 + wn * 64 + d]);
        }
      }
    }
  } else if (z == 1) {
    // K: bias + RoPE + bf16, attn layout [bh][d>>3][tok][d&7]
    const int h = bn * 2 + wn;
    const int nb = bn * 128 + wn * 64;
#pragma unroll
    for (int i = 0; i < 4; i++) {
      int m0 = bm * 128 + wm * 64 + i * 16 + g * 4;
#pragma unroll
      for (int r = 0; r < 4; r++) {
        int m = m0 + r;
        int tok = m & (SEQ - 1);
        int b = m >> 11;
        size_t bhb = (size_t)(b * NHEAD + h) * 8;
#pragma unroll
        for (int j = 0; j < 2; j++) {
          int d = j * 16 + c;
          float x1 = acc[i][j][r] + bias[nb + d];
          float x2 = acc[i][j + 2][r] + bias[nb + d + 32];
          float cs = cosT[tok * 32 + d];
          float sn = sinT[tok * 32 + d];
          Kg[(bhb + (d >> 3)) * (SEQ * 8) + tok * 8 + (d & 7)]     = f2bf(x1 * cs - x2 * sn);
          Kg[(bhb + 4 + (d >> 3)) * (SEQ * 8) + tok * 8 + (d & 7)] = f2bf(x2 * cs + x1 * sn);
        }
      }
    }
  } else {
    // Q: bias + RoPE + bf16 + 0.125*log2e scale, layout [bh][l][d]
    const float qs = 0.180336880f;  // 0.125 * log2(e)
    const int h = bn * 2 + wn;
    const int nb = bn * 128 + wn * 64;
#pragma unroll
    for (int i = 0; i < 4; i++) {
      int m0 = bm * 128 + wm * 64 + i * 16 + g * 4;
#pragma unroll
      for (int r = 0; r < 4; r++) {
        int m = m0 + r;
        int tok = m & (SEQ - 1);
        int b = m >> 11;
        size_t obase = ((size_t)(b * NHEAD + h) * SEQ + tok) * HD;
#pragma unroll
        for (int j = 0; j < 2; j++) {
          int d = j * 16 + c;
          float x1 = acc[i][j][r] + bias[nb + d];
          float x2 = acc[i][j + 2][r] + bias[nb + d + 32];
          float cs = cosT[tok * 32 + d];
          float sn = sinT[tok * 32 + d];
          Qr[obase + d]      = f2bf((x1 * cs - x2 * sn) * qs);
          Qr[obase + d + 32] = f2bf((x2 * cs + x1 * sn) * qs);
        }
      }
    }
  }
}

// ---------------- output GEMM: out = Cb(M,K) * Wo(N,K)^T + bo, f32 out ----------------
// BN=64 (was 128): grid (32,16)=512 blocks = 2 blocks/CU (was 1) -- occupancy fix.
__global__ __launch_bounds__(256) void k_gemm_out(
    const u16* __restrict__ A, const u16* __restrict__ W,
    const float* __restrict__ bias, float* __restrict__ out) {
  __shared__ __attribute__((aligned(16))) u16 As[128 * 64];  // 16KB
  __shared__ __attribute__((aligned(16))) u16 Bs[64 * 64];   // 8KB
  const int tid = threadIdx.x;
  const int lane = tid & 63, wid = tid >> 6;
  const int g = lane >> 4, c = lane & 15;
  const int wm = wid >> 1, wn = wid & 1;
  const int bm = blockIdx.x, bn = blockIdx.y;

  const f32x4 vz = {0.f, 0.f, 0.f, 0.f};
  f32x4 acc[4][2];
#pragma unroll
  for (int i = 0; i < 4; i++)
#pragma unroll
    for (int j = 0; j < 2; j++) acc[i][j] = vz;

  const int srow = tid >> 3;
  const int scb = tid & 7;

  for (int kt = 0; kt < DM / 64; ++kt) {
    __syncthreads();
#pragma unroll
    for (int cc = 0; cc < 4; ++cc) {
      int row = cc * 32 + srow;
      int sc = scb ^ (row & 7);
      gll16(A + (size_t)(bm * 128 + row) * DM + kt * 64 + sc * 8,
            &As[cc * 2048 + wid * 512]);
    }
#pragma unroll
    for (int cc = 0; cc < 2; ++cc) {
      int row = cc * 32 + srow;
      int sc = scb ^ (row & 7);
      gll16(W + (size_t)(bn * 64 + row) * DM + kt * 64 + sc * 8,
            &Bs[cc * 2048 + wid * 512]);
    }
    __syncthreads();
#pragma unroll
    for (int kk = 0; kk < 2; ++kk) {
      bf16v8 av[4], bv[2];
#pragma unroll
      for (int i = 0; i < 4; i++) {
        int row = wm * 64 + i * 16 + c;
        int sc = (kk * 4 + g) ^ (row & 7);
        av[i] = *(const bf16v8*)&As[row * 64 + sc * 8];
      }
#pragma unroll
      for (int j = 0; j < 2; j++) {
        int row = wn * 32 + j * 16 + c;
        int sc = (kk * 4 + g) ^ (row & 7);
        bv[j] = *(const bf16v8*)&Bs[row * 64 + sc * 8];
      }
#pragma unroll
      for (int i = 0; i < 4; i++)
#pragma unroll
        for (int j = 0; j < 2; j++)
          acc[i][j] = __builtin_amdgcn_mfma_f32_16x16x32_bf16(av[i], bv[j], acc[i][j], 0, 0, 0);
    }
  }

#pragma unroll
  for (int i = 0; i < 4; i++) {
    int m = bm * 128 + wm * 64 + i * 16 + g * 4;
#pragma unroll
    for (int j = 0; j < 2; j++) {
      int n = bn * 64 + wn * 32 + j * 16 + c;
      float bb = bias[n];
#pragma unroll
      for (int r = 0; r < 4; r++)
        out[(size_t)(m + r) * DM + n] = acc[i][j][r] + bb;
    }
  }
}

// ---------------- flash attention v15: BARRIER-FREE, LDS-free K/V ----------------
// R13/14 diagnosis: per-iter __syncthreads + vmcnt(0) drain serialized the pipes
// even at 4 waves/SIMD. The R12 subtiled Kg/Vg layouts make direct global fragment
// loads PERFECTLY coalesced (each kf/vf inst = 2 x 512B contiguous segments), unlike
// R9's 16-line scatter. So: no K/V LDS, no loop barriers; waves fully independent;
// latency hidden by TLP (16 waves/CU) + compiler cross-iter pipelining. K/V (16MB)
// is L3-resident; per-bh slices L2-warm. LDS (33KB) used only for the team merge.
__global__ __launch_bounds__(512, 4) void k_attn(
    const u16* __restrict__ Qb, const u16* __restrict__ Kg,
    const u16* __restrict__ Vg, u16* __restrict__ Cb) {
  __shared__ float Mo[8192];   // 32KB merge buffer
  __shared__ float Ml[128];
  const int tid = threadIdx.x, lane = tid & 63, wid = tid >> 6;
  const int hh = lane >> 5, ln = lane & 31;
  const int team = wid >> 2, lw = wid & 3;
  const int bh = blockIdx.y;
  const int q0 = blockIdx.x * 128 + lw * 32;

  const u16* Kh = Kg + (size_t)bh * 8 * SEQ * 8;
  const u16* Vh = Vg + (size_t)bh * 256 * 64 * 8;

  // Q as B-operand (in regs): col q = q0+ln, k(d) = ks*16 + hh*8 + e
  const u16* Qh = Qb + ((size_t)bh * SEQ + q0 + ln) * HD + hh * 8;
  bf16v8 qf[4];
#pragma unroll
  for (int ks = 0; ks < 4; ks++) qf[ks] = *(const bf16v8*)(Qh + ks * 16);

  f32x16 octx[2];
#pragma unroll
  for (int dsub = 0; dsub < 2; dsub++)
#pragma unroll
    for (int r = 0; r < 16; r++) octx[dsub][r] = 0.f;
  f32x4 lac4 = {0.f, 0.f, 0.f, 0.f};

  const int kvbase = team * 1024;

  for (int it = 0; it < 16; ++it) {
    const int kv0 = kvbase + it * 64;

    bf16v8 pb[4];  // PV B-frags, one per 16-kv slice
#pragma unroll
    for (int s = 0; s < 2; s++) {
      f32x16 sT;
#pragma unroll
      for (int r = 0; r < 16; r++) sT[r] = 0.f;
#pragma unroll
      for (int ks = 0; ks < 4; ks++) {
        bf16v8 kf = *(const bf16v8*)(Kh +
            ((size_t)(ks * 2 + hh) * SEQ + kv0 + s * 32 + ln) * 8);
        sT = __builtin_amdgcn_mfma_f32_32x32x16_bf16(kf, qf[ks], sT, 0, 0, 0);
      }
      float p[16];
#pragma unroll
      for (int r = 0; r < 16; r++) {
        p[r] = __builtin_amdgcn_exp2f(sT[r]);
        lac4[r & 3] += p[r];
      }
#pragma unroll
      for (int ksl = 0; ksl < 2; ksl++) {
        const int bb = ksl * 8;
        u32 Aw, Bw, Cw, Dw;
        asm("v_cvt_pk_bf16_f32 %0, %1, %2" : "=v"(Aw) : "v"(p[bb + 0]), "v"(p[bb + 1]));
        asm("v_cvt_pk_bf16_f32 %0, %1, %2" : "=v"(Bw) : "v"(p[bb + 2]), "v"(p[bb + 3]));
        asm("v_cvt_pk_bf16_f32 %0, %1, %2" : "=v"(Cw) : "v"(p[bb + 4]), "v"(p[bb + 5]));
        asm("v_cvt_pk_bf16_f32 %0, %1, %2" : "=v"(Dw) : "v"(p[bb + 6]), "v"(p[bb + 7]));
        u32x2 r02 = __builtin_amdgcn_permlane32_swap(Aw, Cw, false, false);
        u32x2 r13 = __builtin_amdgcn_permlane32_swap(Bw, Dw, false, false);
        union { u32 w[4]; bf16v8 v; } pu;
        pu.w[0] = r02[0]; pu.w[1] = r13[0]; pu.w[2] = r02[1]; pu.w[3] = r13[1];
        pb[s * 2 + ksl] = pu.v;
      }
    }

    // PV: O^T = mfma32(V^T-frag(A), P-frag(B)); V direct from global, P in regs
#pragma unroll
    for (int dsub = 0; dsub < 2; dsub++)
#pragma unroll
      for (int ks = 0; ks < 4; ks++) {
        bf16v8 vf = *(const bf16v8*)(Vh +
            ((size_t)((kv0 >> 3) + ks * 2 + hh) * 64 + dsub * 32 + ln) * 8);
        octx[dsub] = __builtin_amdgcn_mfma_f32_32x32x16_bf16(vf, pb[ks], octx[dsub], 0, 0, 0);
      }
  }

  // per-team l for q=ln (combine the two hh kv-row groups)
  float lacc = (lac4[0] + lac4[1]) + (lac4[2] + lac4[3]);
  float lt_own = lacc + __shfl_xor(lacc, 32);

  // merge: team 1 -> LDS, team 0 adds + normalizes + writes.
  if (team == 1) {
#pragma unroll
    for (int dsub = 0; dsub < 2; dsub++)
#pragma unroll
      for (int rr = 0; rr < 4; rr++) {
        f32x4 v = {octx[dsub][rr * 4 + 0], octx[dsub][rr * 4 + 1],
                   octx[dsub][rr * 4 + 2], octx[dsub][rr * 4 + 3]};
        *(f32x4*)&Mo[(((lw * 8) + dsub * 4 + rr) * 64 + lane) * 4] = v;
      }
    if (hh == 0) Ml[lw * 32 + ln] = lt_own;
  }
  __syncthreads();
  if (team == 0) {
    float lt = lt_own + Ml[lw * 32 + ln];
    float inv = 1.0f / lt;
    const int b = bh >> 4, h = bh & 15;
    const int q = q0 + ln;
    u16* orow = Cb + ((size_t)(b * SEQ + q)) * DM + h * HD;
#pragma unroll
    for (int dsub = 0; dsub < 2; dsub++)
#pragma unroll
      for (int rr = 0; rr < 4; rr++) {
        f32x4 m = *(const f32x4*)&Mo[(((lw * 8) + dsub * 4 + rr) * 64 + lane) * 4];
        int d0 = dsub * 32 + rr * 8 + hh * 4;
        bf16v4 o4 = {(__bf16)((octx[dsub][rr * 4 + 0] + m[0]) * inv),
                     (__bf16)((octx[dsub][rr * 4 + 1] + m[1]) * inv),
                     (__bf16)((octx[dsub][rr * 4 + 2] + m[2]) * inv),
                     (__bf16)((octx[dsub][rr * 4 + 3] + m[3]) * inv)};
        *(bf16v4*)(orow + d0) = o4;
      }
  }
}

extern "C" void kernel_launch(void* const* d_in, const int* in_sizes, int n_in,
                              void* d_out, int out_size, void* d_ws, size_t ws_size,
                              hipStream_t stream) {
  (void)in_sizes; (void)n_in; (void)out_size;
  const float* x  = (const float*)d_in[0];
  const float* Wq = (const float*)d_in[1];
  const float* bq = (const float*)d_in[2];
  const float* Wk = (const float*)d_in[3];
  const float* bk = (const float*)d_in[4];
  const float* Wv = (const float*)d_in[5];
  const float* bv = (const float*)d_in[6];
  const float* Wo = (const float*)d_in[7];
  const float* bo = (const float*)d_in[8];
  float* out = (float*)d_out;
  char* ws = (char*)d_ws;
  const size_t MB = 1024ull * 1024ull;

  if (ws_size < 49ull * MB) return;  // diagnostic: absmax == max|ref| means ws too small

  float* cosT = (float*)(ws);                      // 256KB
  float* sinT = (float*)(ws + 256 * 1024);         // 256KB
  u16* Xb  = (u16*)(ws + 512 * 1024);              // 8MB (reused as Cb)
  u16* Wqb = (u16*)(ws + 512 * 1024 + 8 * MB);     // 2MB
  u16* Wkb = (u16*)(ws + 512 * 1024 + 10 * MB);
  u16* Wvb = (u16*)(ws + 512 * 1024 + 12 * MB);
  u16* Wob = (u16*)(ws + 512 * 1024 + 14 * MB);
  u16* Qr  = (u16*)(ws + 512 * 1024 + 24 * MB);    // 8MB
  u16* Kg  = (u16*)(ws + 512 * 1024 + 32 * MB);    // 8MB (subtiled layout)
  u16* Vg  = (u16*)(ws + 512 * 1024 + 40 * MB);    // 8MB (subtiled layout)
  u16* Cb  = Xb;

  // one prep dispatch: x cvt (4096 blocks) + 4 W cvt (4096) + rope table (256)
  k_prep<<<dim3(8448), 256, 0, stream>>>(x, Wq, Wk, Wv, Wo, Xb, Wqb, Wkb, Wvb, Wob,
                                         cosT, sinT);

  dim3 gp(MROWS / 128, DM / 128, 3);
  k_gemm_qkv<<<gp, 256, 0, stream>>>(Xb, Wqb, Wkb, Wvb, bq, bk, bv, Qr, Kg, Vg,
                                     cosT, sinT);

  dim3 ga(SEQ / 128, NBATCH * NHEAD);
  k_attn<<<ga, 512, 0, stream>>>(Qr, Kg, Vg, Cb);

  dim3 go(MROWS / 128, DM / 64);
  k_gemm_out<<<go, 256, 0, stream>>>(Cb, Wob, bo, out);
}

// Round 16
// 104.841 us; speedup vs baseline: 1.3871x; 1.3871x over previous
//
#include <hip/hip_runtime.h>

typedef unsigned short u16;
typedef unsigned int u32;
typedef __attribute__((ext_vector_type(8))) __bf16 bf16v8;
typedef __attribute__((ext_vector_type(4))) __bf16 bf16v4;
typedef __attribute__((ext_vector_type(4))) float f32x4;
typedef __attribute__((ext_vector_type(16))) float f32x16;
typedef __attribute__((ext_vector_type(2))) unsigned u32x2;

#define SEQ    2048
#define NBATCH 2
#define NHEAD  16
#define HD     64
#define DM     1024
#define MROWS  4096   // NBATCH*SEQ

__device__ __forceinline__ u16 f2bf(float f) {
  unsigned int u = __float_as_uint(f);
  u += 0x7FFFu + ((u >> 16) & 1u);   // round-to-nearest-even
  return (u16)(u >> 16);
}

__device__ __forceinline__ void gll16(const void* g, void* l) {
  __builtin_amdgcn_global_load_lds(
      (__attribute__((address_space(1))) void*)g,
      (__attribute__((address_space(3))) void*)l, 16, 0, 0);
}

// ---------------- fused prep: x->bf16, 4x W->bf16, RoPE table (1 dispatch) ----------
__global__ __launch_bounds__(256) void k_prep(
    const float* __restrict__ x,
    const float* __restrict__ Wq, const float* __restrict__ Wk,
    const float* __restrict__ Wv, const float* __restrict__ Wo,
    u16* __restrict__ Xb, u16* __restrict__ Wqb, u16* __restrict__ Wkb,
    u16* __restrict__ Wvb, u16* __restrict__ Wob,
    float* __restrict__ cosT, float* __restrict__ sinT) {
  int bid = blockIdx.x;
  if (bid < MROWS * DM / 1024) {            // 4096 blocks: x f32->bf16
    int i = bid * 256 + threadIdx.x;
    float4 v = ((const float4*)x)[i];
    ushort4 o;
    o.x = f2bf(v.x); o.y = f2bf(v.y); o.z = f2bf(v.z); o.w = f2bf(v.w);
    ((ushort4*)Xb)[i] = o;
    return;
  }
  bid -= MROWS * DM / 1024;
  if (bid < 4 * (DM * DM / 1024)) {         // 4096 blocks: weights f32->bf16
    int seg = bid >> 10;
    int i = (bid & 1023) * 256 + threadIdx.x;
    const float* src = (seg == 0) ? Wq : (seg == 1) ? Wk : (seg == 2) ? Wv : Wo;
    u16* dst = (seg == 0) ? Wqb : (seg == 1) ? Wkb : (seg == 2) ? Wvb : Wob;
    float4 v = ((const float4*)src)[i];
    ushort4 o;
    o.x = f2bf(v.x); o.y = f2bf(v.y); o.z = f2bf(v.z); o.w = f2bf(v.w);
    ((ushort4*)dst)[i] = o;
    return;
  }
  bid -= 4 * (DM * DM / 1024);
  int idx = bid * 256 + threadIdx.x;        // 256 blocks: RoPE cos/sin table
  int l = idx >> 5, d = idx & 31;
  float inv = 1.0f / powf(10000.0f, (float)d * (1.0f / 32.0f));
  float ang = (float)l * inv;
  float s, c;
  sincosf(ang, &s, &c);
  cosT[idx] = c;
  sinT[idx] = s;
}

// ---------------- fused QKV projection: bias + RoPE(Q,K) + bf16 + attn layouts ------
// v16: BM=64 (was 128) -> grid (64,8,3)=1536 blocks = 6 blocks/CU (was 3), LDS 24KB.
// R15 occupancy analysis: qkv was grid-bound at 3 blocks/CU (occupancy 14.5%).
// z=0: Q -> Qr [bh][l][d], RoPE, x(0.125*log2e); z=1: K -> Kg [bh][d/8][kv][8d];
// z=2: V -> Vg [bh][kv/8][d][8kv]. Head-pairing intact: wn-wave owns one 64-col
// head, RoPE pair (d,d+32) = acc[i][j]/acc[i][j+2] in the same lane.
__global__ __launch_bounds__(256) void k_gemm_qkv(
    const u16* __restrict__ A,
    const u16* W0, const u16* W1, const u16* W2,
    const float* b0, const float* b1, const float* b2,
    u16* __restrict__ Qr, u16* __restrict__ Kg, u16* __restrict__ Vg,
    const float* __restrict__ cosT, const float* __restrict__ sinT) {
  __shared__ __attribute__((aligned(16))) u16 As[64 * 64];    // 8KB
  __shared__ __attribute__((aligned(16))) u16 Bs[128 * 64];   // 16KB
  const int z = blockIdx.z;
  const u16* W = (z == 0) ? W0 : ((z == 1) ? W1 : W2);
  const float* bias = (z == 0) ? b0 : ((z == 1) ? b1 : b2);

  const int tid = threadIdx.x;
  const int lane = tid & 63, wid = tid >> 6;
  const int g = lane >> 4, c = lane & 15;
  const int wm = wid >> 1, wn = wid & 1;
  const int bm = blockIdx.x, bn = blockIdx.y;

  const f32x4 vz = {0.f, 0.f, 0.f, 0.f};
  f32x4 acc[2][4];
#pragma unroll
  for (int i = 0; i < 2; i++)
#pragma unroll
    for (int j = 0; j < 4; j++) acc[i][j] = vz;

  const int srow = tid >> 3;
  const int scb = tid & 7;

  for (int kt = 0; kt < DM / 64; ++kt) {
    __syncthreads();
#pragma unroll
    for (int cc = 0; cc < 2; ++cc) {
      int row = cc * 32 + srow;
      int sc = scb ^ (row & 7);
      gll16(A + (size_t)(bm * 64 + row) * DM + kt * 64 + sc * 8,
            &As[cc * 2048 + wid * 512]);
    }
#pragma unroll
    for (int cc = 0; cc < 4; ++cc) {
      int row = cc * 32 + srow;
      int sc = scb ^ (row & 7);
      gll16(W + (size_t)(bn * 128 + row) * DM + kt * 64 + sc * 8,
            &Bs[cc * 2048 + wid * 512]);
    }
    __syncthreads();
#pragma unroll
    for (int kk = 0; kk < 2; ++kk) {
      bf16v8 av[2], bv[4];
#pragma unroll
      for (int i = 0; i < 2; i++) {
        int row = wm * 32 + i * 16 + c;
        int sc = (kk * 4 + g) ^ (row & 7);
        av[i] = *(const bf16v8*)&As[row * 64 + sc * 8];
      }
#pragma unroll
      for (int j = 0; j < 4; j++) {
        int row = wn * 64 + j * 16 + c;
        int sc = (kk * 4 + g) ^ (row & 7);
        bv[j] = *(const bf16v8*)&Bs[row * 64 + sc * 8];
      }
#pragma unroll
      for (int i = 0; i < 2; i++)
#pragma unroll
        for (int j = 0; j < 4; j++)
          acc[i][j] = __builtin_amdgcn_mfma_f32_16x16x32_bf16(av[i], bv[j], acc[i][j], 0, 0, 0);
    }
  }

  if (z == 2) {
    // V: bias + bf16, write directly in attn layout [bh][kv>>3][d][kv&7]
    const int h = bn * 2 + wn;
#pragma unroll
    for (int i = 0; i < 2; i++) {
      int m0 = bm * 64 + wm * 32 + i * 16 + g * 4;
#pragma unroll
      for (int r = 0; r < 4; r++) {
        int m = m0 + r;
        int tok = m & (SEQ - 1);
        int b = m >> 11;
        size_t base = ((size_t)((b * NHEAD + h) * 256 + (tok >> 3)) * 64) * 8 + (tok & 7);
#pragma unroll
        for (int j = 0; j < 4; j++) {
          int d = j * 16 + c;
          Vg[base + (size_t)d * 8] = f2bf(acc[i][j][r] + bias[bn * 128 + wn * 64 + d]);
        }
      }
    }
  } else if (z == 1) {
    // K: bias + RoPE + bf16, attn layout [bh][d>>3][tok][d&7]
    const int h = bn * 2 + wn;
    const int nb = bn * 128 + wn * 64;
#pragma unroll
    for (int i = 0; i < 2; i++) {
      int m0 = bm * 64 + wm * 32 + i * 16 + g * 4;
#pragma unroll
      for (int r = 0; r < 4; r++) {
        int m = m0 + r;
        int tok = m & (SEQ - 1);
        int b = m >> 11;
        size_t bhb = (size_t)(b * NHEAD + h) * 8;
#pragma unroll
        for (int j = 0; j < 2; j++) {
          int d = j * 16 + c;
          float x1 = acc[i][j][r] + bias[nb + d];
          float x2 = acc[i][j + 2][r] + bias[nb + d + 32];
          float cs = cosT[tok * 32 + d];
          float sn = sinT[tok * 32 + d];
          Kg[(bhb + (d >> 3)) * (SEQ * 8) + tok * 8 + (d & 7)]     = f2bf(x1 * cs - x2 * sn);
          Kg[(bhb + 4 + (d >> 3)) * (SEQ * 8) + tok * 8 + (d & 7)] = f2bf(x2 * cs + x1 * sn);
        }
      }
    }
  } else {
    // Q: bias + RoPE + bf16 + 0.125*log2e scale, layout [bh][l][d]
    const float qs = 0.180336880f;  // 0.125 * log2(e)
    const int h = bn * 2 + wn;
    const int nb = bn * 128 + wn * 64;
#pragma unroll
    for (int i = 0; i < 2; i++) {
      int m0 = bm * 64 + wm * 32 + i * 16 + g * 4;
#pragma unroll
      for (int r = 0; r < 4; r++) {
        int m = m0 + r;
        int tok = m & (SEQ - 1);
        int b = m >> 11;
        size_t obase = ((size_t)(b * NHEAD + h) * SEQ + tok) * HD;
#pragma unroll
        for (int j = 0; j < 2; j++) {
          int d = j * 16 + c;
          float x1 = acc[i][j][r] + bias[nb + d];
          float x2 = acc[i][j + 2][r] + bias[nb + d + 32];
          float cs = cosT[tok * 32 + d];
          float sn = sinT[tok * 32 + d];
          Qr[obase + d]      = f2bf((x1 * cs - x2 * sn) * qs);
          Qr[obase + d + 32] = f2bf((x2 * cs + x1 * sn) * qs);
        }
      }
    }
  }
}

// ---------------- output GEMM: out = Cb(M,K) * Wo(N,K)^T + bo, f32 out ----------------
// BN=64: grid (32,16)=512 blocks = 2 blocks/CU.
__global__ __launch_bounds__(256) void k_gemm_out(
    const u16* __restrict__ A, const u16* __restrict__ W,
    const float* __restrict__ bias, float* __restrict__ out) {
  __shared__ __attribute__((aligned(16))) u16 As[128 * 64];  // 16KB
  __shared__ __attribute__((aligned(16))) u16 Bs[64 * 64];   // 8KB
  const int tid = threadIdx.x;
  const int lane = tid & 63, wid = tid >> 6;
  const int g = lane >> 4, c = lane & 15;
  const int wm = wid >> 1, wn = wid & 1;
  const int bm = blockIdx.x, bn = blockIdx.y;

  const f32x4 vz = {0.f, 0.f, 0.f, 0.f};
  f32x4 acc[4][2];
#pragma unroll
  for (int i = 0; i < 4; i++)
#pragma unroll
    for (int j = 0; j < 2; j++) acc[i][j] = vz;

  const int srow = tid >> 3;
  const int scb = tid & 7;

  for (int kt = 0; kt < DM / 64; ++kt) {
    __syncthreads();
#pragma unroll
    for (int cc = 0; cc < 4; ++cc) {
      int row = cc * 32 + srow;
      int sc = scb ^ (row & 7);
      gll16(A + (size_t)(bm * 128 + row) * DM + kt * 64 + sc * 8,
            &As[cc * 2048 + wid * 512]);
    }
#pragma unroll
    for (int cc = 0; cc < 2; ++cc) {
      int row = cc * 32 + srow;
      int sc = scb ^ (row & 7);
      gll16(W + (size_t)(bn * 64 + row) * DM + kt * 64 + sc * 8,
            &Bs[cc * 2048 + wid * 512]);
    }
    __syncthreads();
#pragma unroll
    for (int kk = 0; kk < 2; ++kk) {
      bf16v8 av[4], bv[2];
#pragma unroll
      for (int i = 0; i < 4; i++) {
        int row = wm * 64 + i * 16 + c;
        int sc = (kk * 4 + g) ^ (row & 7);
        av[i] = *(const bf16v8*)&As[row * 64 + sc * 8];
      }
#pragma unroll
      for (int j = 0; j < 2; j++) {
        int row = wn * 32 + j * 16 + c;
        int sc = (kk * 4 + g) ^ (row & 7);
        bv[j] = *(const bf16v8*)&Bs[row * 64 + sc * 8];
      }
#pragma unroll
      for (int i = 0; i < 4; i++)
#pragma unroll
        for (int j = 0; j < 2; j++)
          acc[i][j] = __builtin_amdgcn_mfma_f32_16x16x32_bf16(av[i], bv[j], acc[i][j], 0, 0, 0);
    }
  }

#pragma unroll
  for (int i = 0; i < 4; i++) {
    int m = bm * 128 + wm * 64 + i * 16 + g * 4;
#pragma unroll
    for (int j = 0; j < 2; j++) {
      int n = bn * 64 + wn * 32 + j * 16 + c;
      float bb = bias[n];
#pragma unroll
      for (int r = 0; r < 4; r++)
        out[(size_t)(m + r) * DM + n] = acc[i][j][r] + bb;
    }
  }
}

// ---------------- flash attention v14 (reverted from v15): in-block kv-split --------
// R15 lesson: LDS staging is a traffic DE-DUPLICATOR (1 tile serves 4 waves) --
// direct-global fragments quadrupled L2 reads and regressed 45->78us. v14 proven.
__global__ __launch_bounds__(512, 4) void k_attn(
    const u16* __restrict__ Qb, const u16* __restrict__ Kg,
    const u16* __restrict__ Vg, u16* __restrict__ Cb) {
  __shared__ __attribute__((aligned(16))) u16 SMEM[32768];  // 64 KB
  const int tid = threadIdx.x, lane = tid & 63, wid = tid >> 6;
  const int hh = lane >> 5, ln = lane & 31;
  const int team = wid >> 2, lw = wid & 3;
  const int bh = blockIdx.y;
  const int q0 = blockIdx.x * 128 + lw * 32;

  // Q as B-operand (in regs): col q = q0+ln, k(d) = ks*16 + hh*8 + e
  const u16* Qh = Qb + ((size_t)bh * SEQ + q0 + ln) * HD + hh * 8;
  bf16v8 qf[4];
#pragma unroll
  for (int ks = 0; ks < 4; ks++) qf[ks] = *(const bf16v8*)(Qh + ks * 16);

  f32x16 octx[2];
#pragma unroll
  for (int dsub = 0; dsub < 2; dsub++)
#pragma unroll
    for (int r = 0; r < 16; r++) octx[dsub][r] = 0.f;
  f32x4 lac4 = {0.f, 0.f, 0.f, 0.f};

  // team LDS: K at (team*2+buf)*8192, V at +4096 (u16 units)
  const int kvbase = team * 1024;

#define STAGE(buf, kv0)                                                              \
  {                                                                                  \
    u16* Kb_ = &SMEM[(team * 2 + (buf)) * 8192];                                     \
    u16* Vb_ = Kb_ + 4096;                                                           \
    _Pragma("unroll") for (int cc = 0; cc < 2; ++cc) {                               \
      int kk = lw * 2 + cc;                                                          \
      gll16(Kg + ((size_t)(bh * 8 + kk) * SEQ + (kv0)) * 8 + lane * 8,               \
            &Kb_[kk * 512]);                                                         \
      gll16(Vg + ((size_t)(bh * 256 + ((kv0) >> 3) + kk) * 64 + lane) * 8,           \
            &Vb_[kk * 512]);                                                         \
    }                                                                                \
  }

  STAGE(0, kvbase);
  __syncthreads();
  int cur = 0;

  for (int it = 0; it < 16; ++it) {
    if (it + 1 < 16) STAGE(cur ^ 1, kvbase + (it + 1) * 64);
    const u16* Kc = &SMEM[(team * 2 + cur) * 8192];
    const u16* Vc = Kc + 4096;

    bf16v8 pb[4];  // PV B-frags, one per 16-kv slice
#pragma unroll
    for (int s = 0; s < 2; s++) {
      f32x16 sT;
#pragma unroll
      for (int r = 0; r < 16; r++) sT[r] = 0.f;
#pragma unroll
      for (int ks = 0; ks < 4; ks++) {
        bf16v8 kf = *(const bf16v8*)&Kc[(ks * 2 + hh) * 512 + (s * 32 + ln) * 8];
        sT = __builtin_amdgcn_mfma_f32_32x32x16_bf16(kf, qf[ks], sT, 0, 0, 0);
      }
      float p[16];
#pragma unroll
      for (int r = 0; r < 16; r++) {
        p[r] = __builtin_amdgcn_exp2f(sT[r]);
        lac4[r & 3] += p[r];
      }
#pragma unroll
      for (int ksl = 0; ksl < 2; ksl++) {
        const int bb = ksl * 8;
        u32 Aw, Bw, Cw, Dw;
        asm("v_cvt_pk_bf16_f32 %0, %1, %2" : "=v"(Aw) : "v"(p[bb + 0]), "v"(p[bb + 1]));
        asm("v_cvt_pk_bf16_f32 %0, %1, %2" : "=v"(Bw) : "v"(p[bb + 2]), "v"(p[bb + 3]));
        asm("v_cvt_pk_bf16_f32 %0, %1, %2" : "=v"(Cw) : "v"(p[bb + 4]), "v"(p[bb + 5]));
        asm("v_cvt_pk_bf16_f32 %0, %1, %2" : "=v"(Dw) : "v"(p[bb + 6]), "v"(p[bb + 7]));
        u32x2 r02 = __builtin_amdgcn_permlane32_swap(Aw, Cw, false, false);
        u32x2 r13 = __builtin_amdgcn_permlane32_swap(Bw, Dw, false, false);
        union { u32 w[4]; bf16v8 v; } pu;
        pu.w[0] = r02[0]; pu.w[1] = r13[0]; pu.w[2] = r02[1]; pu.w[3] = r13[1];
        pb[s * 2 + ksl] = pu.v;
      }
    }

    // PV: O^T = mfma32(V^T-frag(A), P-frag(B)); V from LDS, P in regs
#pragma unroll
    for (int dsub = 0; dsub < 2; dsub++)
#pragma unroll
      for (int ks = 0; ks < 4; ks++) {
        bf16v8 vf = *(const bf16v8*)&Vc[(ks * 2 + hh) * 512 + (dsub * 32 + ln) * 8];
        octx[dsub] = __builtin_amdgcn_mfma_f32_32x32x16_bf16(vf, pb[ks], octx[dsub], 0, 0, 0);
      }

    __syncthreads();
    cur ^= 1;
  }

  // per-team l for q=ln (combine the two hh kv-row groups)
  float lacc = (lac4[0] + lac4[1]) + (lac4[2] + lac4[3]);
  float lt_own = lacc + __shfl_xor(lacc, 32);

  // merge: team 1 -> LDS, team 0 adds + normalizes + writes.
  float* Mo = (float*)SMEM;              // 32 KB
  float* Ml = ((float*)SMEM) + 8192;     // 512 B
  __syncthreads();
  if (team == 1) {
#pragma unroll
    for (int dsub = 0; dsub < 2; dsub++)
#pragma unroll
      for (int rr = 0; rr < 4; rr++) {
        f32x4 v = {octx[dsub][rr * 4 + 0], octx[dsub][rr * 4 + 1],
                   octx[dsub][rr * 4 + 2], octx[dsub][rr * 4 + 3]};
        *(f32x4*)&Mo[(((lw * 8) + dsub * 4 + rr) * 64 + lane) * 4] = v;
      }
    if (hh == 0) Ml[lw * 32 + ln] = lt_own;
  }
  __syncthreads();
  if (team == 0) {
    float lt = lt_own + Ml[lw * 32 + ln];
    float inv = 1.0f / lt;
    const int b = bh >> 4, h = bh & 15;
    const int q = q0 + ln;
    u16* orow = Cb + ((size_t)(b * SEQ + q)) * DM + h * HD;
#pragma unroll
    for (int dsub = 0; dsub < 2; dsub++)
#pragma unroll
      for (int rr = 0; rr < 4; rr++) {
        f32x4 m = *(const f32x4*)&Mo[(((lw * 8) + dsub * 4 + rr) * 64 + lane) * 4];
        int d0 = dsub * 32 + rr * 8 + hh * 4;
        bf16v4 o4 = {(__bf16)((octx[dsub][rr * 4 + 0] + m[0]) * inv),
                     (__bf16)((octx[dsub][rr * 4 + 1] + m[1]) * inv),
                     (__bf16)((octx[dsub][rr * 4 + 2] + m[2]) * inv),
                     (__bf16)((octx[dsub][rr * 4 + 3] + m[3]) * inv)};
        *(bf16v4*)(orow + d0) = o4;
      }
  }
}

extern "C" void kernel_launch(void* const* d_in, const int* in_sizes, int n_in,
                              void* d_out, int out_size, void* d_ws, size_t ws_size,
                              hipStream_t stream) {
  (void)in_sizes; (void)n_in; (void)out_size;
  const float* x  = (const float*)d_in[0];
  const float* Wq = (const float*)d_in[1];
  const float* bq = (const float*)d_in[2];
  const float* Wk = (const float*)d_in[3];
  const float* bk = (const float*)d_in[4];
  const float* Wv = (const float*)d_in[5];
  const float* bv = (const float*)d_in[6];
  const float* Wo = (const float*)d_in[7];
  const float* bo = (const float*)d_in[8];
  float* out = (float*)d_out;
  char* ws = (char*)d_ws;
  const size_t MB = 1024ull * 1024ull;

  if (ws_size < 49ull * MB) return;  // diagnostic: absmax == max|ref| means ws too small

  float* cosT = (float*)(ws);                      // 256KB
  float* sinT = (float*)(ws + 256 * 1024);         // 256KB
  u16* Xb  = (u16*)(ws + 512 * 1024);              // 8MB (reused as Cb)
  u16* Wqb = (u16*)(ws + 512 * 1024 + 8 * MB);     // 2MB
  u16* Wkb = (u16*)(ws + 512 * 1024 + 10 * MB);
  u16* Wvb = (u16*)(ws + 512 * 1024 + 12 * MB);
  u16* Wob = (u16*)(ws + 512 * 1024 + 14 * MB);
  u16* Qr  = (u16*)(ws + 512 * 1024 + 24 * MB);    // 8MB
  u16* Kg  = (u16*)(ws + 512 * 1024 + 32 * MB);    // 8MB (subtiled layout)
  u16* Vg  = (u16*)(ws + 512 * 1024 + 40 * MB);    // 8MB (subtiled layout)
  u16* Cb  = Xb;

  // one prep dispatch: x cvt (4096 blocks) + 4 W cvt (4096) + rope table (256)
  k_prep<<<dim3(8448), 256, 0, stream>>>(x, Wq, Wk, Wv, Wo, Xb, Wqb, Wkb, Wvb, Wob,
                                         cosT, sinT);

  dim3 gp(MROWS / 64, DM / 128, 3);
  k_gemm_qkv<<<gp, 256, 0, stream>>>(Xb, Wqb, Wkb, Wvb, bq, bk, bv, Qr, Kg, Vg,
                                     cosT, sinT);

  dim3 ga(SEQ / 128, NBATCH * NHEAD);
  k_attn<<<ga, 512, 0, stream>>>(Qr, Kg, Vg, Cb);

  dim3 go(MROWS / 128, DM / 64);
  k_gemm_out<<<go, 256, 0, stream>>>(Cb, Wob, bo, out);
}

// Round 17
// 104.523 us; speedup vs baseline: 1.3913x; 1.0030x over previous
//
#include <hip/hip_runtime.h>

typedef unsigned short u16;
typedef unsigned int u32;
typedef __attribute__((ext_vector_type(8))) __bf16 bf16v8;
typedef __attribute__((ext_vector_type(4))) __bf16 bf16v4;
typedef __attribute__((ext_vector_type(4))) float f32x4;
typedef __attribute__((ext_vector_type(16))) float f32x16;
typedef __attribute__((ext_vector_type(2))) unsigned u32x2;

#define SEQ    2048
#define NBATCH 2
#define NHEAD  16
#define HD     64
#define DM     1024
#define MROWS  4096   // NBATCH*SEQ

__device__ __forceinline__ u16 f2bf(float f) {
  unsigned int u = __float_as_uint(f);
  u += 0x7FFFu + ((u >> 16) & 1u);   // round-to-nearest-even
  return (u16)(u >> 16);
}

__device__ __forceinline__ void gll16(const void* g, void* l) {
  __builtin_amdgcn_global_load_lds(
      (__attribute__((address_space(1))) void*)g,
      (__attribute__((address_space(3))) void*)l, 16, 0, 0);
}

// ---------------- fused prep: x->bf16, 4x W->bf16, RoPE table (1 dispatch) ----------
__global__ __launch_bounds__(256) void k_prep(
    const float* __restrict__ x,
    const float* __restrict__ Wq, const float* __restrict__ Wk,
    const float* __restrict__ Wv, const float* __restrict__ Wo,
    u16* __restrict__ Xb, u16* __restrict__ Wqb, u16* __restrict__ Wkb,
    u16* __restrict__ Wvb, u16* __restrict__ Wob,
    float* __restrict__ cosT, float* __restrict__ sinT) {
  int bid = blockIdx.x;
  if (bid < MROWS * DM / 1024) {            // 4096 blocks: x f32->bf16
    int i = bid * 256 + threadIdx.x;
    float4 v = ((const float4*)x)[i];
    ushort4 o;
    o.x = f2bf(v.x); o.y = f2bf(v.y); o.z = f2bf(v.z); o.w = f2bf(v.w);
    ((ushort4*)Xb)[i] = o;
    return;
  }
  bid -= MROWS * DM / 1024;
  if (bid < 4 * (DM * DM / 1024)) {         // 4096 blocks: weights f32->bf16
    int seg = bid >> 10;
    int i = (bid & 1023) * 256 + threadIdx.x;
    const float* src = (seg == 0) ? Wq : (seg == 1) ? Wk : (seg == 2) ? Wv : Wo;
    u16* dst = (seg == 0) ? Wqb : (seg == 1) ? Wkb : (seg == 2) ? Wvb : Wob;
    float4 v = ((const float4*)src)[i];
    ushort4 o;
    o.x = f2bf(v.x); o.y = f2bf(v.y); o.z = f2bf(v.z); o.w = f2bf(v.w);
    ((ushort4*)dst)[i] = o;
    return;
  }
  bid -= 4 * (DM * DM / 1024);
  int idx = bid * 256 + threadIdx.x;        // 256 blocks: RoPE cos/sin table
  int l = idx >> 5, d = idx & 31;
  float inv = 1.0f / powf(10000.0f, (float)d * (1.0f / 32.0f));
  float ang = (float)l * inv;
  float s, c;
  sincosf(ang, &s, &c);
  cosT[idx] = c;
  sinT[idx] = s;
}

// ---------------- fused QKV projection: bias + RoPE(Q,K) + bf16 + attn layouts ------
// BM=64: grid (64,8,3)=1536 blocks = 6 blocks/CU, LDS 24KB (R16 occupancy fix).
// z=0: Q -> Qr [bh][l][d], RoPE, x(0.125*log2e); z=1: K -> Kg [bh][d/8][kv][8d];
// z=2: V -> Vg [bh][kv/8][d][8kv]. RoPE pair (d,d+32) = acc[i][j]/acc[i][j+2] in-lane.
__global__ __launch_bounds__(256) void k_gemm_qkv(
    const u16* __restrict__ A,
    const u16* W0, const u16* W1, const u16* W2,
    const float* b0, const float* b1, const float* b2,
    u16* __restrict__ Qr, u16* __restrict__ Kg, u16* __restrict__ Vg,
    const float* __restrict__ cosT, const float* __restrict__ sinT) {
  __shared__ __attribute__((aligned(16))) u16 As[64 * 64];    // 8KB
  __shared__ __attribute__((aligned(16))) u16 Bs[128 * 64];   // 16KB
  const int z = blockIdx.z;
  const u16* W = (z == 0) ? W0 : ((z == 1) ? W1 : W2);
  const float* bias = (z == 0) ? b0 : ((z == 1) ? b1 : b2);

  const int tid = threadIdx.x;
  const int lane = tid & 63, wid = tid >> 6;
  const int g = lane >> 4, c = lane & 15;
  const int wm = wid >> 1, wn = wid & 1;
  const int bm = blockIdx.x, bn = blockIdx.y;

  const f32x4 vz = {0.f, 0.f, 0.f, 0.f};
  f32x4 acc[2][4];
#pragma unroll
  for (int i = 0; i < 2; i++)
#pragma unroll
    for (int j = 0; j < 4; j++) acc[i][j] = vz;

  const int srow = tid >> 3;
  const int scb = tid & 7;

  for (int kt = 0; kt < DM / 64; ++kt) {
    __syncthreads();
#pragma unroll
    for (int cc = 0; cc < 2; ++cc) {
      int row = cc * 32 + srow;
      int sc = scb ^ (row & 7);
      gll16(A + (size_t)(bm * 64 + row) * DM + kt * 64 + sc * 8,
            &As[cc * 2048 + wid * 512]);
    }
#pragma unroll
    for (int cc = 0; cc < 4; ++cc) {
      int row = cc * 32 + srow;
      int sc = scb ^ (row & 7);
      gll16(W + (size_t)(bn * 128 + row) * DM + kt * 64 + sc * 8,
            &Bs[cc * 2048 + wid * 512]);
    }
    __syncthreads();
#pragma unroll
    for (int kk = 0; kk < 2; ++kk) {
      bf16v8 av[2], bv[4];
#pragma unroll
      for (int i = 0; i < 2; i++) {
        int row = wm * 32 + i * 16 + c;
        int sc = (kk * 4 + g) ^ (row & 7);
        av[i] = *(const bf16v8*)&As[row * 64 + sc * 8];
      }
#pragma unroll
      for (int j = 0; j < 4; j++) {
        int row = wn * 64 + j * 16 + c;
        int sc = (kk * 4 + g) ^ (row & 7);
        bv[j] = *(const bf16v8*)&Bs[row * 64 + sc * 8];
      }
#pragma unroll
      for (int i = 0; i < 2; i++)
#pragma unroll
        for (int j = 0; j < 4; j++)
          acc[i][j] = __builtin_amdgcn_mfma_f32_16x16x32_bf16(av[i], bv[j], acc[i][j], 0, 0, 0);
    }
  }

  if (z == 2) {
    const int h = bn * 2 + wn;
#pragma unroll
    for (int i = 0; i < 2; i++) {
      int m0 = bm * 64 + wm * 32 + i * 16 + g * 4;
#pragma unroll
      for (int r = 0; r < 4; r++) {
        int m = m0 + r;
        int tok = m & (SEQ - 1);
        int b = m >> 11;
        size_t base = ((size_t)((b * NHEAD + h) * 256 + (tok >> 3)) * 64) * 8 + (tok & 7);
#pragma unroll
        for (int j = 0; j < 4; j++) {
          int d = j * 16 + c;
          Vg[base + (size_t)d * 8] = f2bf(acc[i][j][r] + bias[bn * 128 + wn * 64 + d]);
        }
      }
    }
  } else if (z == 1) {
    const int h = bn * 2 + wn;
    const int nb = bn * 128 + wn * 64;
#pragma unroll
    for (int i = 0; i < 2; i++) {
      int m0 = bm * 64 + wm * 32 + i * 16 + g * 4;
#pragma unroll
      for (int r = 0; r < 4; r++) {
        int m = m0 + r;
        int tok = m & (SEQ - 1);
        int b = m >> 11;
        size_t bhb = (size_t)(b * NHEAD + h) * 8;
#pragma unroll
        for (int j = 0; j < 2; j++) {
          int d = j * 16 + c;
          float x1 = acc[i][j][r] + bias[nb + d];
          float x2 = acc[i][j + 2][r] + bias[nb + d + 32];
          float cs = cosT[tok * 32 + d];
          float sn = sinT[tok * 32 + d];
          Kg[(bhb + (d >> 3)) * (SEQ * 8) + tok * 8 + (d & 7)]     = f2bf(x1 * cs - x2 * sn);
          Kg[(bhb + 4 + (d >> 3)) * (SEQ * 8) + tok * 8 + (d & 7)] = f2bf(x2 * cs + x1 * sn);
        }
      }
    }
  } else {
    const float qs = 0.180336880f;  // 0.125 * log2(e)
    const int h = bn * 2 + wn;
    const int nb = bn * 128 + wn * 64;
#pragma unroll
    for (int i = 0; i < 2; i++) {
      int m0 = bm * 64 + wm * 32 + i * 16 + g * 4;
#pragma unroll
      for (int r = 0; r < 4; r++) {
        int m = m0 + r;
        int tok = m & (SEQ - 1);
        int b = m >> 11;
        size_t obase = ((size_t)(b * NHEAD + h) * SEQ + tok) * HD;
#pragma unroll
        for (int j = 0; j < 2; j++) {
          int d = j * 16 + c;
          float x1 = acc[i][j][r] + bias[nb + d];
          float x2 = acc[i][j + 2][r] + bias[nb + d + 32];
          float cs = cosT[tok * 32 + d];
          float sn = sinT[tok * 32 + d];
          Qr[obase + d]      = f2bf((x1 * cs - x2 * sn) * qs);
          Qr[obase + d + 32] = f2bf((x2 * cs + x1 * sn) * qs);
        }
      }
    }
  }
}

// ---------------- output GEMM: out = Cb(M,K) * Wo(N,K)^T + bo, f32 out ----------------
// v17: 64x64 tile -> grid (64,16)=1024 blocks = 4 blocks/CU (was 2, grid-bound).
// A-sharing blocks are 64 apart in linear id -> same XCD under round-robin.
__global__ __launch_bounds__(256) void k_gemm_out(
    const u16* __restrict__ A, const u16* __restrict__ W,
    const float* __restrict__ bias, float* __restrict__ out) {
  __shared__ __attribute__((aligned(16))) u16 As[64 * 64];   // 8KB
  __shared__ __attribute__((aligned(16))) u16 Bs[64 * 64];   // 8KB
  const int tid = threadIdx.x;
  const int lane = tid & 63, wid = tid >> 6;
  const int g = lane >> 4, c = lane & 15;
  const int wm = wid >> 1, wn = wid & 1;
  const int bm = blockIdx.x, bn = blockIdx.y;

  const f32x4 vz = {0.f, 0.f, 0.f, 0.f};
  f32x4 acc[2][2];
#pragma unroll
  for (int i = 0; i < 2; i++)
#pragma unroll
    for (int j = 0; j < 2; j++) acc[i][j] = vz;

  const int srow = tid >> 3;
  const int scb = tid & 7;

  for (int kt = 0; kt < DM / 64; ++kt) {
    __syncthreads();
#pragma unroll
    for (int cc = 0; cc < 2; ++cc) {
      int row = cc * 32 + srow;
      int sc = scb ^ (row & 7);
      gll16(A + (size_t)(bm * 64 + row) * DM + kt * 64 + sc * 8,
            &As[cc * 2048 + wid * 512]);
      gll16(W + (size_t)(bn * 64 + row) * DM + kt * 64 + sc * 8,
            &Bs[cc * 2048 + wid * 512]);
    }
    __syncthreads();
#pragma unroll
    for (int kk = 0; kk < 2; ++kk) {
      bf16v8 av[2], bv[2];
#pragma unroll
      for (int i = 0; i < 2; i++) {
        int row = wm * 32 + i * 16 + c;
        int sc = (kk * 4 + g) ^ (row & 7);
        av[i] = *(const bf16v8*)&As[row * 64 + sc * 8];
      }
#pragma unroll
      for (int j = 0; j < 2; j++) {
        int row = wn * 32 + j * 16 + c;
        int sc = (kk * 4 + g) ^ (row & 7);
        bv[j] = *(const bf16v8*)&Bs[row * 64 + sc * 8];
      }
#pragma unroll
      for (int i = 0; i < 2; i++)
#pragma unroll
        for (int j = 0; j < 2; j++)
          acc[i][j] = __builtin_amdgcn_mfma_f32_16x16x32_bf16(av[i], bv[j], acc[i][j], 0, 0, 0);
    }
  }

#pragma unroll
  for (int i = 0; i < 2; i++) {
    int m = bm * 64 + wm * 32 + i * 16 + g * 4;
#pragma unroll
    for (int j = 0; j < 2; j++) {
      int n = bn * 64 + wn * 32 + j * 16 + c;
      float bb = bias[n];
#pragma unroll
      for (int r = 0; r < 4; r++)
        out[(size_t)(m + r) * DM + n] = acc[i][j][r] + bb;
    }
  }
}

// ---------------- flash attention v17: v14 + XCD pin + ones-MFMA l + setprio --------
// XCD pin (proven FETCH 70->12MB in R9): 1-D grid, id%8 = XCD (m09 round-robin);
// bh = (id&7)*4 + ((id>>3)&3) pins 4 heads/XCD -> K/V 2MB < 4MB L2.
// l via MFMA: lone = mfma32(ones_A, pb_B) -> D[i][q] = sum_k P[k][q], all rows
// identical, summed over ALL 32 k-rows -> lt_own = lone[0], no VALU adds, no shfl.
// setprio(1) around MFMA clusters (T5; 2-team split gives wave role diversity).
__global__ __launch_bounds__(512, 4) void k_attn(
    const u16* __restrict__ Qb, const u16* __restrict__ Kg,
    const u16* __restrict__ Vg, u16* __restrict__ Cb) {
  __shared__ __attribute__((aligned(16))) u16 SMEM[32768];  // 64 KB
  const int tid = threadIdx.x, lane = tid & 63, wid = tid >> 6;
  const int hh = lane >> 5, ln = lane & 31;
  const int team = wid >> 2, lw = wid & 3;
  const int id = blockIdx.x;                       // 0..511
  const int bh = (id & 7) * 4 + ((id >> 3) & 3);   // 4 heads per XCD
  const int q0 = (id >> 5) * 128 + lw * 32;

  // Q as B-operand (in regs): col q = q0+ln, k(d) = ks*16 + hh*8 + e
  const u16* Qh = Qb + ((size_t)bh * SEQ + q0 + ln) * HD + hh * 8;
  bf16v8 qf[4];
#pragma unroll
  for (int ks = 0; ks < 4; ks++) qf[ks] = *(const bf16v8*)(Qh + ks * 16);

  const __bf16 one = (__bf16)1.0f;
  const bf16v8 ones = {one, one, one, one, one, one, one, one};

  f32x16 octx[2], lone;
#pragma unroll
  for (int dsub = 0; dsub < 2; dsub++)
#pragma unroll
    for (int r = 0; r < 16; r++) octx[dsub][r] = 0.f;
#pragma unroll
  for (int r = 0; r < 16; r++) lone[r] = 0.f;

  // team LDS: K at (team*2+buf)*8192, V at +4096 (u16 units)
  const int kvbase = team * 1024;

#define STAGE(buf, kv0)                                                              \
  {                                                                                  \
    u16* Kb_ = &SMEM[(team * 2 + (buf)) * 8192];                                     \
    u16* Vb_ = Kb_ + 4096;                                                           \
    _Pragma("unroll") for (int cc = 0; cc < 2; ++cc) {                               \
      int kk = lw * 2 + cc;                                                          \
      gll16(Kg + ((size_t)(bh * 8 + kk) * SEQ + (kv0)) * 8 + lane * 8,               \
            &Kb_[kk * 512]);                                                         \
      gll16(Vg + ((size_t)(bh * 256 + ((kv0) >> 3) + kk) * 64 + lane) * 8,           \
            &Vb_[kk * 512]);                                                         \
    }                                                                                \
  }

  STAGE(0, kvbase);
  __syncthreads();
  int cur = 0;

  for (int it = 0; it < 16; ++it) {
    if (it + 1 < 16) STAGE(cur ^ 1, kvbase + (it + 1) * 64);
    const u16* Kc = &SMEM[(team * 2 + cur) * 8192];
    const u16* Vc = Kc + 4096;

    bf16v8 pb[4];  // PV B-frags, one per 16-kv slice
#pragma unroll
    for (int s = 0; s < 2; s++) {
      f32x16 sT;
#pragma unroll
      for (int r = 0; r < 16; r++) sT[r] = 0.f;
      __builtin_amdgcn_s_setprio(1);
#pragma unroll
      for (int ks = 0; ks < 4; ks++) {
        bf16v8 kf = *(const bf16v8*)&Kc[(ks * 2 + hh) * 512 + (s * 32 + ln) * 8];
        sT = __builtin_amdgcn_mfma_f32_32x32x16_bf16(kf, qf[ks], sT, 0, 0, 0);
      }
      __builtin_amdgcn_s_setprio(0);
      float p[16];
#pragma unroll
      for (int r = 0; r < 16; r++) p[r] = __builtin_amdgcn_exp2f(sT[r]);
#pragma unroll
      for (int ksl = 0; ksl < 2; ksl++) {
        const int bb = ksl * 8;
        u32 Aw, Bw, Cw, Dw;
        asm("v_cvt_pk_bf16_f32 %0, %1, %2" : "=v"(Aw) : "v"(p[bb + 0]), "v"(p[bb + 1]));
        asm("v_cvt_pk_bf16_f32 %0, %1, %2" : "=v"(Bw) : "v"(p[bb + 2]), "v"(p[bb + 3]));
        asm("v_cvt_pk_bf16_f32 %0, %1, %2" : "=v"(Cw) : "v"(p[bb + 4]), "v"(p[bb + 5]));
        asm("v_cvt_pk_bf16_f32 %0, %1, %2" : "=v"(Dw) : "v"(p[bb + 6]), "v"(p[bb + 7]));
        u32x2 r02 = __builtin_amdgcn_permlane32_swap(Aw, Cw, false, false);
        u32x2 r13 = __builtin_amdgcn_permlane32_swap(Bw, Dw, false, false);
        union { u32 w[4]; bf16v8 v; } pu;
        pu.w[0] = r02[0]; pu.w[1] = r13[0]; pu.w[2] = r02[1]; pu.w[3] = r13[1];
        pb[s * 2 + ksl] = pu.v;
      }
    }

    // PV + l: O^T = mfma32(V^T-frag(A), P-frag(B)); lone = mfma32(ones, P-frag)
    __builtin_amdgcn_s_setprio(1);
#pragma unroll
    for (int ks = 0; ks < 4; ks++) {
      lone = __builtin_amdgcn_mfma_f32_32x32x16_bf16(ones, pb[ks], lone, 0, 0, 0);
#pragma unroll
      for (int dsub = 0; dsub < 2; dsub++) {
        bf16v8 vf = *(const bf16v8*)&Vc[(ks * 2 + hh) * 512 + (dsub * 32 + ln) * 8];
        octx[dsub] = __builtin_amdgcn_mfma_f32_32x32x16_bf16(vf, pb[ks], octx[dsub], 0, 0, 0);
      }
    }
    __builtin_amdgcn_s_setprio(0);

    __syncthreads();
    cur ^= 1;
  }

  // l for q=ln over this team's kv range (MFMA summed all k-rows; rows identical)
  float lt_own = lone[0];

  // merge: team 1 -> LDS, team 0 adds + normalizes + writes.
  float* Mo = (float*)SMEM;              // 32 KB
  float* Ml = ((float*)SMEM) + 8192;     // 512 B
  __syncthreads();
  if (team == 1) {
#pragma unroll
    for (int dsub = 0; dsub < 2; dsub++)
#pragma unroll
      for (int rr = 0; rr < 4; rr++) {
        f32x4 v = {octx[dsub][rr * 4 + 0], octx[dsub][rr * 4 + 1],
                   octx[dsub][rr * 4 + 2], octx[dsub][rr * 4 + 3]};
        *(f32x4*)&Mo[(((lw * 8) + dsub * 4 + rr) * 64 + lane) * 4] = v;
      }
    if (hh == 0) Ml[lw * 32 + ln] = lt_own;
  }
  __syncthreads();
  if (team == 0) {
    float lt = lt_own + Ml[lw * 32 + ln];
    float inv = 1.0f / lt;
    const int b = bh >> 4, h = bh & 15;
    const int q = q0 + ln;
    u16* orow = Cb + ((size_t)(b * SEQ + q)) * DM + h * HD;
#pragma unroll
    for (int dsub = 0; dsub < 2; dsub++)
#pragma unroll
      for (int rr = 0; rr < 4; rr++) {
        f32x4 m = *(const f32x4*)&Mo[(((lw * 8) + dsub * 4 + rr) * 64 + lane) * 4];
        int d0 = dsub * 32 + rr * 8 + hh * 4;
        bf16v4 o4 = {(__bf16)((octx[dsub][rr * 4 + 0] + m[0]) * inv),
                     (__bf16)((octx[dsub][rr * 4 + 1] + m[1]) * inv),
                     (__bf16)((octx[dsub][rr * 4 + 2] + m[2]) * inv),
                     (__bf16)((octx[dsub][rr * 4 + 3] + m[3]) * inv)};
        *(bf16v4*)(orow + d0) = o4;
      }
  }
}

extern "C" void kernel_launch(void* const* d_in, const int* in_sizes, int n_in,
                              void* d_out, int out_size, void* d_ws, size_t ws_size,
                              hipStream_t stream) {
  (void)in_sizes; (void)n_in; (void)out_size;
  const float* x  = (const float*)d_in[0];
  const float* Wq = (const float*)d_in[1];
  const float* bq = (const float*)d_in[2];
  const float* Wk = (const float*)d_in[3];
  const float* bk = (const float*)d_in[4];
  const float* Wv = (const float*)d_in[5];
  const float* bv = (const float*)d_in[6];
  const float* Wo = (const float*)d_in[7];
  const float* bo = (const float*)d_in[8];
  float* out = (float*)d_out;
  char* ws = (char*)d_ws;
  const size_t MB = 1024ull * 1024ull;

  if (ws_size < 49ull * MB) return;  // diagnostic: absmax == max|ref| means ws too small

  float* cosT = (float*)(ws);                      // 256KB
  float* sinT = (float*)(ws + 256 * 1024);         // 256KB
  u16* Xb  = (u16*)(ws + 512 * 1024);              // 8MB (reused as Cb)
  u16* Wqb = (u16*)(ws + 512 * 1024 + 8 * MB);     // 2MB
  u16* Wkb = (u16*)(ws + 512 * 1024 + 10 * MB);
  u16* Wvb = (u16*)(ws + 512 * 1024 + 12 * MB);
  u16* Wob = (u16*)(ws + 512 * 1024 + 14 * MB);
  u16* Qr  = (u16*)(ws + 512 * 1024 + 24 * MB);    // 8MB
  u16* Kg  = (u16*)(ws + 512 * 1024 + 32 * MB);    // 8MB (subtiled layout)
  u16* Vg  = (u16*)(ws + 512 * 1024 + 40 * MB);    // 8MB (subtiled layout)
  u16* Cb  = Xb;

  // one prep dispatch: x cvt (4096 blocks) + 4 W cvt (4096) + rope table (256)
  k_prep<<<dim3(8448), 256, 0, stream>>>(x, Wq, Wk, Wv, Wo, Xb, Wqb, Wkb, Wvb, Wob,
                                         cosT, sinT);

  dim3 gp(MROWS / 64, DM / 128, 3);
  k_gemm_qkv<<<gp, 256, 0, stream>>>(Xb, Wqb, Wkb, Wvb, bq, bk, bv, Qr, Kg, Vg,
                                     cosT, sinT);

  k_attn<<<dim3(SEQ / 128 * NBATCH * NHEAD), 512, 0, stream>>>(Qr, Kg, Vg, Cb);

  dim3 go(MROWS / 64, DM / 64);
  k_gemm_out<<<go, 256, 0, stream>>>(Cb, Wob, bo, out);
}

// Round 18
// 104.188 us; speedup vs baseline: 1.3958x; 1.0032x over previous
//
#include <hip/hip_runtime.h>

typedef unsigned short u16;
typedef unsigned int u32;
typedef __attribute__((ext_vector_type(8))) __bf16 bf16v8;
typedef __attribute__((ext_vector_type(4))) __bf16 bf16v4;
typedef __attribute__((ext_vector_type(4))) float f32x4;
typedef __attribute__((ext_vector_type(16))) float f32x16;
typedef __attribute__((ext_vector_type(2))) unsigned u32x2;

#define SEQ    2048
#define NBATCH 2
#define NHEAD  16
#define HD     64
#define DM     1024
#define MROWS  4096   // NBATCH*SEQ

__device__ __forceinline__ u16 f2bf(float f) {
  unsigned int u = __float_as_uint(f);
  u += 0x7FFFu + ((u >> 16) & 1u);   // round-to-nearest-even
  return (u16)(u >> 16);
}

__device__ __forceinline__ void gll16(const void* g, void* l) {
  __builtin_amdgcn_global_load_lds(
      (__attribute__((address_space(1))) void*)g,
      (__attribute__((address_space(3))) void*)l, 16, 0, 0);
}

// ---------------- fused prep: x->bf16, 4x W->bf16, RoPE table (1 dispatch) ----------
__global__ __launch_bounds__(256) void k_prep(
    const float* __restrict__ x,
    const float* __restrict__ Wq, const float* __restrict__ Wk,
    const float* __restrict__ Wv, const float* __restrict__ Wo,
    u16* __restrict__ Xb, u16* __restrict__ Wqb, u16* __restrict__ Wkb,
    u16* __restrict__ Wvb, u16* __restrict__ Wob,
    float* __restrict__ cosT, float* __restrict__ sinT) {
  int bid = blockIdx.x;
  if (bid < MROWS * DM / 1024) {            // 4096 blocks: x f32->bf16
    int i = bid * 256 + threadIdx.x;
    float4 v = ((const float4*)x)[i];
    ushort4 o;
    o.x = f2bf(v.x); o.y = f2bf(v.y); o.z = f2bf(v.z); o.w = f2bf(v.w);
    ((ushort4*)Xb)[i] = o;
    return;
  }
  bid -= MROWS * DM / 1024;
  if (bid < 4 * (DM * DM / 1024)) {         // 4096 blocks: weights f32->bf16
    int seg = bid >> 10;
    int i = (bid & 1023) * 256 + threadIdx.x;
    const float* src = (seg == 0) ? Wq : (seg == 1) ? Wk : (seg == 2) ? Wv : Wo;
    u16* dst = (seg == 0) ? Wqb : (seg == 1) ? Wkb : (seg == 2) ? Wvb : Wob;
    float4 v = ((const float4*)src)[i];
    ushort4 o;
    o.x = f2bf(v.x); o.y = f2bf(v.y); o.z = f2bf(v.z); o.w = f2bf(v.w);
    ((ushort4*)dst)[i] = o;
    return;
  }
  bid -= 4 * (DM * DM / 1024);
  int idx = bid * 256 + threadIdx.x;        // 256 blocks: RoPE cos/sin table
  int l = idx >> 5, d = idx & 31;
  float inv = 1.0f / powf(10000.0f, (float)d * (1.0f / 32.0f));
  float ang = (float)l * inv;
  float s, c;
  sincosf(ang, &s, &c);
  cosT[idx] = c;
  sinT[idx] = s;
}

// ---------------- fused QKV projection: bias + RoPE(Q,K) + bf16 + attn layouts ------
// BM=64: grid (64,8,3)=1536 blocks = 6 blocks/CU, LDS 24KB (R16 occupancy fix).
// z=0: Q -> Qr [bh][l][d], RoPE, x(0.125*log2e); z=1: K -> Kg [bh][d/8][kv][8d];
// z=2: V -> Vg [bh][kv/8][d][8kv]. RoPE pair (d,d+32) = acc[i][j]/acc[i][j+2] in-lane.
__global__ __launch_bounds__(256) void k_gemm_qkv(
    const u16* __restrict__ A,
    const u16* W0, const u16* W1, const u16* W2,
    const float* b0, const float* b1, const float* b2,
    u16* __restrict__ Qr, u16* __restrict__ Kg, u16* __restrict__ Vg,
    const float* __restrict__ cosT, const float* __restrict__ sinT) {
  __shared__ __attribute__((aligned(16))) u16 As[64 * 64];    // 8KB
  __shared__ __attribute__((aligned(16))) u16 Bs[128 * 64];   // 16KB
  const int z = blockIdx.z;
  const u16* W = (z == 0) ? W0 : ((z == 1) ? W1 : W2);
  const float* bias = (z == 0) ? b0 : ((z == 1) ? b1 : b2);

  const int tid = threadIdx.x;
  const int lane = tid & 63, wid = tid >> 6;
  const int g = lane >> 4, c = lane & 15;
  const int wm = wid >> 1, wn = wid & 1;
  const int bm = blockIdx.x, bn = blockIdx.y;

  const f32x4 vz = {0.f, 0.f, 0.f, 0.f};
  f32x4 acc[2][4];
#pragma unroll
  for (int i = 0; i < 2; i++)
#pragma unroll
    for (int j = 0; j < 4; j++) acc[i][j] = vz;

  const int srow = tid >> 3;
  const int scb = tid & 7;

  for (int kt = 0; kt < DM / 64; ++kt) {
    __syncthreads();
#pragma unroll
    for (int cc = 0; cc < 2; ++cc) {
      int row = cc * 32 + srow;
      int sc = scb ^ (row & 7);
      gll16(A + (size_t)(bm * 64 + row) * DM + kt * 64 + sc * 8,
            &As[cc * 2048 + wid * 512]);
    }
#pragma unroll
    for (int cc = 0; cc < 4; ++cc) {
      int row = cc * 32 + srow;
      int sc = scb ^ (row & 7);
      gll16(W + (size_t)(bn * 128 + row) * DM + kt * 64 + sc * 8,
            &Bs[cc * 2048 + wid * 512]);
    }
    __syncthreads();
#pragma unroll
    for (int kk = 0; kk < 2; ++kk) {
      bf16v8 av[2], bv[4];
#pragma unroll
      for (int i = 0; i < 2; i++) {
        int row = wm * 32 + i * 16 + c;
        int sc = (kk * 4 + g) ^ (row & 7);
        av[i] = *(const bf16v8*)&As[row * 64 + sc * 8];
      }
#pragma unroll
      for (int j = 0; j < 4; j++) {
        int row = wn * 64 + j * 16 + c;
        int sc = (kk * 4 + g) ^ (row & 7);
        bv[j] = *(const bf16v8*)&Bs[row * 64 + sc * 8];
      }
#pragma unroll
      for (int i = 0; i < 2; i++)
#pragma unroll
        for (int j = 0; j < 4; j++)
          acc[i][j] = __builtin_amdgcn_mfma_f32_16x16x32_bf16(av[i], bv[j], acc[i][j], 0, 0, 0);
    }
  }

  if (z == 2) {
    const int h = bn * 2 + wn;
#pragma unroll
    for (int i = 0; i < 2; i++) {
      int m0 = bm * 64 + wm * 32 + i * 16 + g * 4;
#pragma unroll
      for (int r = 0; r < 4; r++) {
        int m = m0 + r;
        int tok = m & (SEQ - 1);
        int b = m >> 11;
        size_t base = ((size_t)((b * NHEAD + h) * 256 + (tok >> 3)) * 64) * 8 + (tok & 7);
#pragma unroll
        for (int j = 0; j < 4; j++) {
          int d = j * 16 + c;
          Vg[base + (size_t)d * 8] = f2bf(acc[i][j][r] + bias[bn * 128 + wn * 64 + d]);
        }
      }
    }
  } else if (z == 1) {
    const int h = bn * 2 + wn;
    const int nb = bn * 128 + wn * 64;
#pragma unroll
    for (int i = 0; i < 2; i++) {
      int m0 = bm * 64 + wm * 32 + i * 16 + g * 4;
#pragma unroll
      for (int r = 0; r < 4; r++) {
        int m = m0 + r;
        int tok = m & (SEQ - 1);
        int b = m >> 11;
        size_t bhb = (size_t)(b * NHEAD + h) * 8;
#pragma unroll
        for (int j = 0; j < 2; j++) {
          int d = j * 16 + c;
          float x1 = acc[i][j][r] + bias[nb + d];
          float x2 = acc[i][j + 2][r] + bias[nb + d + 32];
          float cs = cosT[tok * 32 + d];
          float sn = sinT[tok * 32 + d];
          Kg[(bhb + (d >> 3)) * (SEQ * 8) + tok * 8 + (d & 7)]     = f2bf(x1 * cs - x2 * sn);
          Kg[(bhb + 4 + (d >> 3)) * (SEQ * 8) + tok * 8 + (d & 7)] = f2bf(x2 * cs + x1 * sn);
        }
      }
    }
  } else {
    const float qs = 0.180336880f;  // 0.125 * log2(e)
    const int h = bn * 2 + wn;
    const int nb = bn * 128 + wn * 64;
#pragma unroll
    for (int i = 0; i < 2; i++) {
      int m0 = bm * 64 + wm * 32 + i * 16 + g * 4;
#pragma unroll
      for (int r = 0; r < 4; r++) {
        int m = m0 + r;
        int tok = m & (SEQ - 1);
        int b = m >> 11;
        size_t obase = ((size_t)(b * NHEAD + h) * SEQ + tok) * HD;
#pragma unroll
        for (int j = 0; j < 2; j++) {
          int d = j * 16 + c;
          float x1 = acc[i][j][r] + bias[nb + d];
          float x2 = acc[i][j + 2][r] + bias[nb + d + 32];
          float cs = cosT[tok * 32 + d];
          float sn = sinT[tok * 32 + d];
          Qr[obase + d]      = f2bf((x1 * cs - x2 * sn) * qs);
          Qr[obase + d + 32] = f2bf((x2 * cs + x1 * sn) * qs);
        }
      }
    }
  }
}

// ---------------- output GEMM: out = Cb(M,K) * Wo(N,K)^T + bo, f32 out ----------------
// v17: 64x64 tile -> grid (64,16)=1024 blocks = 4 blocks/CU (was 2, grid-bound).
// A-sharing blocks are 64 apart in linear id -> same XCD under round-robin.
__global__ __launch_bounds__(256) void k_gemm_out(
    const u16* __restrict__ A, const u16* __restrict__ W,
    const float* __restrict__ bias, float* __restrict__ out) {
  __shared__ __attribute__((aligned(16))) u16 As[64 * 64];   // 8KB
  __shared__ __attribute__((aligned(16))) u16 Bs[64 * 64];   // 8KB
  const int tid = threadIdx.x;
  const int lane = tid & 63, wid = tid >> 6;
  const int g = lane >> 4, c = lane & 15;
  const int wm = wid >> 1, wn = wid & 1;
  const int bm = blockIdx.x, bn = blockIdx.y;

  const f32x4 vz = {0.f, 0.f, 0.f, 0.f};
  f32x4 acc[2][2];
#pragma unroll
  for (int i = 0; i < 2; i++)
#pragma unroll
    for (int j = 0; j < 2; j++) acc[i][j] = vz;

  const int srow = tid >> 3;
  const int scb = tid & 7;

  for (int kt = 0; kt < DM / 64; ++kt) {
    __syncthreads();
#pragma unroll
    for (int cc = 0; cc < 2; ++cc) {
      int row = cc * 32 + srow;
      int sc = scb ^ (row & 7);
      gll16(A + (size_t)(bm * 64 + row) * DM + kt * 64 + sc * 8,
            &As[cc * 2048 + wid * 512]);
      gll16(W + (size_t)(bn * 64 + row) * DM + kt * 64 + sc * 8,
            &Bs[cc * 2048 + wid * 512]);
    }
    __syncthreads();
#pragma unroll
    for (int kk = 0; kk < 2; ++kk) {
      bf16v8 av[2], bv[2];
#pragma unroll
      for (int i = 0; i < 2; i++) {
        int row = wm * 32 + i * 16 + c;
        int sc = (kk * 4 + g) ^ (row & 7);
        av[i] = *(const bf16v8*)&As[row * 64 + sc * 8];
      }
#pragma unroll
      for (int j = 0; j < 2; j++) {
        int row = wn * 32 + j * 16 + c;
        int sc = (kk * 4 + g) ^ (row & 7);
        bv[j] = *(const bf16v8*)&Bs[row * 64 + sc * 8];
      }
#pragma unroll
      for (int i = 0; i < 2; i++)
#pragma unroll
        for (int j = 0; j < 2; j++)
          acc[i][j] = __builtin_amdgcn_mfma_f32_16x16x32_bf16(av[i], bv[j], acc[i][j], 0, 0, 0);
    }
  }

#pragma unroll
  for (int i = 0; i < 2; i++) {
    int m = bm * 64 + wm * 32 + i * 16 + g * 4;
#pragma unroll
    for (int j = 0; j < 2; j++) {
      int n = bn * 64 + wn * 32 + j * 16 + c;
      float bb = bias[n];
#pragma unroll
      for (int r = 0; r < 4; r++)
        out[(size_t)(m + r) * DM + n] = acc[i][j][r] + bb;
    }
  }
}

// ---------------- flash attention v17: v14 + XCD pin + ones-MFMA l + setprio --------
// XCD pin (proven FETCH 70->12MB in R9): 1-D grid, id%8 = XCD (m09 round-robin);
// bh = (id&7)*4 + ((id>>3)&3) pins 4 heads/XCD -> K/V 2MB < 4MB L2.
// l via MFMA: lone = mfma32(ones_A, pb_B) -> D[i][q] = sum_k P[k][q], all rows
// identical, summed over ALL 32 k-rows -> lt_own = lone[0], no VALU adds, no shfl.
// setprio(1) around MFMA clusters (T5; 2-team split gives wave role diversity).
__global__ __launch_bounds__(512, 4) void k_attn(
    const u16* __restrict__ Qb, const u16* __restrict__ Kg,
    const u16* __restrict__ Vg, u16* __restrict__ Cb) {
  __shared__ __attribute__((aligned(16))) u16 SMEM[32768];  // 64 KB
  const int tid = threadIdx.x, lane = tid & 63, wid = tid >> 6;
  const int hh = lane >> 5, ln = lane & 31;
  const int team = wid >> 2, lw = wid & 3;
  const int id = blockIdx.x;                       // 0..511
  const int bh = (id & 7) * 4 + ((id >> 3) & 3);   // 4 heads per XCD
  const int q0 = (id >> 5) * 128 + lw * 32;

  // Q as B-operand (in regs): col q = q0+ln, k(d) = ks*16 + hh*8 + e
  const u16* Qh = Qb + ((size_t)bh * SEQ + q0 + ln) * HD + hh * 8;
  bf16v8 qf[4];
#pragma unroll
  for (int ks = 0; ks < 4; ks++) qf[ks] = *(const bf16v8*)(Qh + ks * 16);

  const __bf16 one = (__bf16)1.0f;
  const bf16v8 ones = {one, one, one, one, one, one, one, one};

  f32x16 octx[2], lone;
#pragma unroll
  for (int dsub = 0; dsub < 2; dsub++)
#pragma unroll
    for (int r = 0; r < 16; r++) octx[dsub][r] = 0.f;
#pragma unroll
  for (int r = 0; r < 16; r++) lone[r] = 0.f;

  // team LDS: K at (team*2+buf)*8192, V at +4096 (u16 units)
  const int kvbase = team * 1024;

#define STAGE(buf, kv0)                                                              \
  {                                                                                  \
    u16* Kb_ = &SMEM[(team * 2 + (buf)) * 8192];                                     \
    u16* Vb_ = Kb_ + 4096;                                                           \
    _Pragma("unroll") for (int cc = 0; cc < 2; ++cc) {                               \
      int kk = lw * 2 + cc;                                                          \
      gll16(Kg + ((size_t)(bh * 8 + kk) * SEQ + (kv0)) * 8 + lane * 8,               \
            &Kb_[kk * 512]);                                                         \
      gll16(Vg + ((size_t)(bh * 256 + ((kv0) >> 3) + kk) * 64 + lane) * 8,           \
            &Vb_[kk * 512]);                                                         \
    }                                                                                \
  }

  STAGE(0, kvbase);
  __syncthreads();
  int cur = 0;

  for (int it = 0; it < 16; ++it) {
    if (it + 1 < 16) STAGE(cur ^ 1, kvbase + (it + 1) * 64);
    const u16* Kc = &SMEM[(team * 2 + cur) * 8192];
    const u16* Vc = Kc + 4096;

    bf16v8 pb[4];  // PV B-frags, one per 16-kv slice
#pragma unroll
    for (int s = 0; s < 2; s++) {
      f32x16 sT;
#pragma unroll
      for (int r = 0; r < 16; r++) sT[r] = 0.f;
      __builtin_amdgcn_s_setprio(1);
#pragma unroll
      for (int ks = 0; ks < 4; ks++) {
        bf16v8 kf = *(const bf16v8*)&Kc[(ks * 2 + hh) * 512 + (s * 32 + ln) * 8];
        sT = __builtin_amdgcn_mfma_f32_32x32x16_bf16(kf, qf[ks], sT, 0, 0, 0);
      }
      __builtin_amdgcn_s_setprio(0);
      float p[16];
#pragma unroll
      for (int r = 0; r < 16; r++) p[r] = __builtin_amdgcn_exp2f(sT[r]);
#pragma unroll
      for (int ksl = 0; ksl < 2; ksl++) {
        const int bb = ksl * 8;
        u32 Aw, Bw, Cw, Dw;
        asm("v_cvt_pk_bf16_f32 %0, %1, %2" : "=v"(Aw) : "v"(p[bb + 0]), "v"(p[bb + 1]));
        asm("v_cvt_pk_bf16_f32 %0, %1, %2" : "=v"(Bw) : "v"(p[bb + 2]), "v"(p[bb + 3]));
        asm("v_cvt_pk_bf16_f32 %0, %1, %2" : "=v"(Cw) : "v"(p[bb + 4]), "v"(p[bb + 5]));
        asm("v_cvt_pk_bf16_f32 %0, %1, %2" : "=v"(Dw) : "v"(p[bb + 6]), "v"(p[bb + 7]));
        u32x2 r02 = __builtin_amdgcn_permlane32_swap(Aw, Cw, false, false);
        u32x2 r13 = __builtin_amdgcn_permlane32_swap(Bw, Dw, false, false);
        union { u32 w[4]; bf16v8 v; } pu;
        pu.w[0] = r02[0]; pu.w[1] = r13[0]; pu.w[2] = r02[1]; pu.w[3] = r13[1];
        pb[s * 2 + ksl] = pu.v;
      }
    }

    // PV + l: O^T = mfma32(V^T-frag(A), P-frag(B)); lone = mfma32(ones, P-frag)
    __builtin_amdgcn_s_setprio(1);
#pragma unroll
    for (int ks = 0; ks < 4; ks++) {
      lone = __builtin_amdgcn_mfma_f32_32x32x16_bf16(ones, pb[ks], lone, 0, 0, 0);
#pragma unroll
      for (int dsub = 0; dsub < 2; dsub++) {
        bf16v8 vf = *(const bf16v8*)&Vc[(ks * 2 + hh) * 512 + (dsub * 32 + ln) * 8];
        octx[dsub] = __builtin_amdgcn_mfma_f32_32x32x16_bf16(vf, pb[ks], octx[dsub], 0, 0, 0);
      }
    }
    __builtin_amdgcn_s_setprio(0);

    __syncthreads();
    cur ^= 1;
  }

  // l for q=ln over this team's kv range (MFMA summed all k-rows; rows identical)
  float lt_own = lone[0];

  // merge: team 1 -> LDS, team 0 adds + normalizes + writes.
  float* Mo = (float*)SMEM;              // 32 KB
  float* Ml = ((float*)SMEM) + 8192;     // 512 B
  __syncthreads();
  if (team == 1) {
#pragma unroll
    for (int dsub = 0; dsub < 2; dsub++)
#pragma unroll
      for (int rr = 0; rr < 4; rr++) {
        f32x4 v = {octx[dsub][rr * 4 + 0], octx[dsub][rr * 4 + 1],
                   octx[dsub][rr * 4 + 2], octx[dsub][rr * 4 + 3]};
        *(f32x4*)&Mo[(((lw * 8) + dsub * 4 + rr) * 64 + lane) * 4] = v;
      }
    if (hh == 0) Ml[lw * 32 + ln] = lt_own;
  }
  __syncthreads();
  if (team == 0) {
    float lt = lt_own + Ml[lw * 32 + ln];
    float inv = 1.0f / lt;
    const int b = bh >> 4, h = bh & 15;
    const int q = q0 + ln;
    u16* orow = Cb + ((size_t)(b * SEQ + q)) * DM + h * HD;
#pragma unroll
    for (int dsub = 0; dsub < 2; dsub++)
#pragma unroll
      for (int rr = 0; rr < 4; rr++) {
        f32x4 m = *(const f32x4*)&Mo[(((lw * 8) + dsub * 4 + rr) * 64 + lane) * 4];
        int d0 = dsub * 32 + rr * 8 + hh * 4;
        bf16v4 o4 = {(__bf16)((octx[dsub][rr * 4 + 0] + m[0]) * inv),
                     (__bf16)((octx[dsub][rr * 4 + 1] + m[1]) * inv),
                     (__bf16)((octx[dsub][rr * 4 + 2] + m[2]) * inv),
                     (__bf16)((octx[dsub][rr * 4 + 3] + m[3]) * inv)};
        *(bf16v4*)(orow + d0) = o4;
      }
  }
}

extern "C" void kernel_launch(void* const* d_in, const int* in_sizes, int n_in,
                              void* d_out, int out_size, void* d_ws, size_t ws_size,
                              hipStream_t stream) {
  (void)in_sizes; (void)n_in; (void)out_size;
  const float* x  = (const float*)d_in[0];
  const float* Wq = (const float*)d_in[1];
  const float* bq = (const float*)d_in[2];
  const float* Wk = (const float*)d_in[3];
  const float* bk = (const float*)d_in[4];
  const float* Wv = (const float*)d_in[5];
  const float* bv = (const float*)d_in[6];
  const float* Wo = (const float*)d_in[7];
  const float* bo = (const float*)d_in[8];
  float* out = (float*)d_out;
  char* ws = (char*)d_ws;
  const size_t MB = 1024ull * 1024ull;

  if (ws_size < 49ull * MB) return;  // diagnostic: absmax == max|ref| means ws too small

  float* cosT = (float*)(ws);                      // 256KB
  float* sinT = (float*)(ws + 256 * 1024);         // 256KB
  u16* Xb  = (u16*)(ws + 512 * 1024);              // 8MB (reused as Cb)
  u16* Wqb = (u16*)(ws + 512 * 1024 + 8 * MB);     // 2MB
  u16* Wkb = (u16*)(ws + 512 * 1024 + 10 * MB);
  u16* Wvb = (u16*)(ws + 512 * 1024 + 12 * MB);
  u16* Wob = (u16*)(ws + 512 * 1024 + 14 * MB);
  u16* Qr  = (u16*)(ws + 512 * 1024 + 24 * MB);    // 8MB
  u16* Kg  = (u16*)(ws + 512 * 1024 + 32 * MB);    // 8MB (subtiled layout)
  u16* Vg  = (u16*)(ws + 512 * 1024 + 40 * MB);    // 8MB (subtiled layout)
  u16* Cb  = Xb;

  // one prep dispatch: x cvt (4096 blocks) + 4 W cvt (4096) + rope table (256)
  k_prep<<<dim3(8448), 256, 0, stream>>>(x, Wq, Wk, Wv, Wo, Xb, Wqb, Wkb, Wvb, Wob,
                                         cosT, sinT);

  dim3 gp(MROWS / 64, DM / 128, 3);
  k_gemm_qkv<<<gp, 256, 0, stream>>>(Xb, Wqb, Wkb, Wvb, bq, bk, bv, Qr, Kg, Vg,
                                     cosT, sinT);

  k_attn<<<dim3(SEQ / 128 * NBATCH * NHEAD), 512, 0, stream>>>(Qr, Kg, Vg, Cb);

  dim3 go(MROWS / 64, DM / 64);
  k_gemm_out<<<go, 256, 0, stream>>>(Cb, Wob, bo, out);
}